// Round 1
// baseline (203.461 us; speedup 1.0000x reference)
//
#include <hip/hip_runtime.h>
#include <hip/hip_bf16.h>
#include <cstddef>

typedef __attribute__((ext_vector_type(8))) short short8;
typedef __attribute__((ext_vector_type(4))) float f32x4;

__device__ inline unsigned short f2bf(float f) {
  unsigned int u = __float_as_uint(f);
  u += 0x7fffu + ((u >> 16) & 1u);
  return (unsigned short)(u >> 16);
}
__device__ inline float bf2f(unsigned short s) {
  return __uint_as_float(((unsigned int)s) << 16);
}

// transpose + cast: src [R,C] f32 -> dst [C,R] bf16
__global__ __launch_bounds__(256) void tcast_kernel(const float* __restrict__ src,
                                                    unsigned short* __restrict__ dst,
                                                    int R, int C) {
  __shared__ float tile[64][65];
  int c0 = blockIdx.x * 64, r0 = blockIdx.y * 64;
  int tx = threadIdx.x & 63, ty = threadIdx.x >> 6;
  for (int i = ty; i < 64; i += 4)
    tile[i][tx] = src[(size_t)(r0 + i) * C + c0 + tx];
  __syncthreads();
  for (int i = ty; i < 64; i += 4)
    dst[(size_t)(c0 + i) * R + r0 + tx] = f2bf(tile[tx][i]);
}

// C = A[M,K] * B[K,N], B given transposed as Bt[N,K] (both bf16 in LDS).
// MODE 0: C0 = bf16 [M,N]
// MODE 1: split kv: col<512 -> C0 bf16 [M,512]; col>=512 -> C1 vt[b,h,d,m] bf16
// MODE 2: C0 = f32 [M,N] + bias
// AF32: A is fp32 in global, converted during staging; else bf16.
template <int MODE, bool AF32>
__global__ __launch_bounds__(256) void gemm_kernel(
    const void* __restrict__ Ap, const unsigned short* __restrict__ Bt,
    void* __restrict__ C0, unsigned short* __restrict__ C1,
    const float* __restrict__ bias, int M, int N, int K) {
  __shared__ unsigned short As[128][72];
  __shared__ unsigned short Bs[128][72];
  const int bm = blockIdx.y * 128, bn = blockIdx.x * 128;
  const int tid = threadIdx.x;
  const int wave = tid >> 6, lane = tid & 63;
  const int wr = (wave >> 1) * 64, wc = (wave & 1) * 64;
  const int l15 = lane & 15, lq = lane >> 4;
  const int sr = tid >> 3, sc = (tid & 7) * 8;
  f32x4 acc[4][4] = {};
  for (int k0 = 0; k0 < K; k0 += 64) {
    __syncthreads();
    for (int p = 0; p < 4; ++p) {
      int r = sr + p * 32;
      if (AF32) {
        const float* Af = (const float*)Ap;
        const float4 f0 = *(const float4*)(Af + (size_t)(bm + r) * K + k0 + sc);
        const float4 f1 = *(const float4*)(Af + (size_t)(bm + r) * K + k0 + sc + 4);
        uint4 u;
        u.x = (unsigned)f2bf(f0.x) | ((unsigned)f2bf(f0.y) << 16);
        u.y = (unsigned)f2bf(f0.z) | ((unsigned)f2bf(f0.w) << 16);
        u.z = (unsigned)f2bf(f1.x) | ((unsigned)f2bf(f1.y) << 16);
        u.w = (unsigned)f2bf(f1.z) | ((unsigned)f2bf(f1.w) << 16);
        *(uint4*)(&As[r][sc]) = u;
      } else {
        const unsigned short* Ab = (const unsigned short*)Ap;
        *(uint4*)(&As[r][sc]) = *(const uint4*)(Ab + (size_t)(bm + r) * K + k0 + sc);
      }
      *(uint4*)(&Bs[r][sc]) = *(const uint4*)(Bt + (size_t)(bn + r) * K + k0 + sc);
    }
    __syncthreads();
    for (int kk = 0; kk < 2; ++kk) {
      short8 af[4], bfr[4];
      for (int mt = 0; mt < 4; ++mt)
        af[mt] = *(const short8*)(&As[wr + mt * 16 + l15][kk * 32 + lq * 8]);
      for (int nt = 0; nt < 4; ++nt)
        bfr[nt] = *(const short8*)(&Bs[wc + nt * 16 + l15][kk * 32 + lq * 8]);
      for (int mt = 0; mt < 4; ++mt)
        for (int nt = 0; nt < 4; ++nt)
          acc[mt][nt] = __builtin_amdgcn_mfma_f32_16x16x32_bf16(af[mt], bfr[nt], acc[mt][nt], 0, 0, 0);
    }
  }
  for (int mt = 0; mt < 4; ++mt)
    for (int nt = 0; nt < 4; ++nt)
      for (int j = 0; j < 4; ++j) {
        int row = bm + wr + mt * 16 + lq * 4 + j;
        int col = bn + wc + nt * 16 + l15;
        float v = acc[mt][nt][j];
        if (MODE == 0) {
          ((unsigned short*)C0)[(size_t)row * N + col] = f2bf(v);
        } else if (MODE == 1) {
          if (col < 512) {
            ((unsigned short*)C0)[(size_t)row * 512 + col] = f2bf(v);
          } else {
            int bb = row >> 11, m = row & 2047;
            int hd = col - 512;  // h*64+d
            C1[((size_t)bb * 512 + hd) * 2048 + m] = f2bf(v);
          }
        } else {
          ((float*)C0)[(size_t)row * N + col] = v + bias[col];
        }
      }
}

// Flash attention. Q/K: [B*2048, 512] bf16 (b,n,h*d). Vt: [B*8*64, 2048] bf16 (b,h,d,m).
// O: [B*2048, 512] bf16. 4 waves x 32 q-rows = 128 q-rows/block, KBLK=64.
__global__ __launch_bounds__(256) void attn_kernel(
    const unsigned short* __restrict__ Q, const unsigned short* __restrict__ Kb,
    const unsigned short* __restrict__ Vt, const int* __restrict__ mask,
    unsigned short* __restrict__ O, float scale) {
  __shared__ unsigned short Ks[64][72];
  __shared__ unsigned short Vs[64][72];
  __shared__ unsigned short Ps[4][32][72];
  __shared__ float Ms[64];
  const int bh = blockIdx.x, b = bh >> 3, h = bh & 7;
  const int qbase = blockIdx.y * 128;
  const int tid = threadIdx.x, wave = tid >> 6, lane = tid & 63;
  const int l15 = lane & 15, lq = lane >> 4;
  const int wrow = qbase + wave * 32;

  short8 qf[2][2];
  for (int rt = 0; rt < 2; ++rt)
    for (int kk = 0; kk < 2; ++kk)
      qf[rt][kk] = *(const short8*)(Q + (size_t)(b * 2048 + wrow + rt * 16 + l15) * 512
                                      + h * 64 + kk * 32 + lq * 8);

  f32x4 o[2][4] = {};
  float mrun[2][4], lrun[2][4];
  for (int rt = 0; rt < 2; ++rt)
    for (int j = 0; j < 4; ++j) { mrun[rt][j] = -1e30f; lrun[rt][j] = 0.f; }

  const int sr = tid >> 3, sc = (tid & 7) * 8;
  const unsigned short* Kg = Kb + (size_t)b * 2048 * 512 + h * 64;
  const unsigned short* Vg = Vt + (size_t)(b * 8 + h) * 64 * 2048;
  const int* mg = mask + b * 2048;

  for (int mb = 0; mb < 2048; mb += 64) {
    __syncthreads();
    for (int p = 0; p < 2; ++p) {
      int r = sr + p * 32;
      *(uint4*)(&Ks[r][sc]) = *(const uint4*)(Kg + (size_t)(mb + r) * 512 + sc);
      *(uint4*)(&Vs[r][sc]) = *(const uint4*)(Vg + (size_t)r * 2048 + mb + sc);
    }
    if (tid < 64) Ms[tid] = (mg[mb + tid] != 0) ? 0.f : -1e30f;
    __syncthreads();

    f32x4 s[2][4] = {};
    for (int kk = 0; kk < 2; ++kk) {
      short8 kf[4];
      for (int ct = 0; ct < 4; ++ct)
        kf[ct] = *(const short8*)(&Ks[ct * 16 + l15][kk * 32 + lq * 8]);
      for (int rt = 0; rt < 2; ++rt)
        for (int ct = 0; ct < 4; ++ct)
          s[rt][ct] = __builtin_amdgcn_mfma_f32_16x16x32_bf16(qf[rt][kk], kf[ct], s[rt][ct], 0, 0, 0);
    }

    for (int rt = 0; rt < 2; ++rt) {
      for (int ct = 0; ct < 4; ++ct) {
        float ma = Ms[ct * 16 + l15];
        for (int j = 0; j < 4; ++j)
          s[rt][ct][j] = s[rt][ct][j] * scale + ma;
      }
      float fac[4], rs[4];
      for (int j = 0; j < 4; ++j) {
        float t = fmaxf(fmaxf(s[rt][0][j], s[rt][1][j]), fmaxf(s[rt][2][j], s[rt][3][j]));
        t = fmaxf(t, __shfl_xor(t, 1));
        t = fmaxf(t, __shfl_xor(t, 2));
        t = fmaxf(t, __shfl_xor(t, 4));
        t = fmaxf(t, __shfl_xor(t, 8));
        float mn = fmaxf(mrun[rt][j], t);
        fac[j] = __expf(mrun[rt][j] - mn);
        mrun[rt][j] = mn;
        rs[j] = 0.f;
      }
      for (int ct = 0; ct < 4; ++ct)
        for (int j = 0; j < 4; ++j) {
          float p = __expf(s[rt][ct][j] - mrun[rt][j]);
          unsigned short pb = f2bf(p);
          Ps[wave][rt * 16 + lq * 4 + j][ct * 16 + l15] = pb;
          rs[j] += bf2f(pb);
        }
      for (int j = 0; j < 4; ++j) {
        float t = rs[j];
        t += __shfl_xor(t, 1);
        t += __shfl_xor(t, 2);
        t += __shfl_xor(t, 4);
        t += __shfl_xor(t, 8);
        lrun[rt][j] = lrun[rt][j] * fac[j] + t;
      }
      for (int dt = 0; dt < 4; ++dt)
        for (int j = 0; j < 4; ++j)
          o[rt][dt][j] *= fac[j];
    }

    for (int kk = 0; kk < 2; ++kk) {
      short8 pf[2];
      for (int rt = 0; rt < 2; ++rt)
        pf[rt] = *(const short8*)(&Ps[wave][rt * 16 + l15][kk * 32 + lq * 8]);
      for (int dt = 0; dt < 4; ++dt) {
        short8 vf = *(const short8*)(&Vs[dt * 16 + l15][kk * 32 + lq * 8]);
        for (int rt = 0; rt < 2; ++rt)
          o[rt][dt] = __builtin_amdgcn_mfma_f32_16x16x32_bf16(pf[rt], vf, o[rt][dt], 0, 0, 0);
      }
    }
  }

  for (int rt = 0; rt < 2; ++rt)
    for (int dt = 0; dt < 4; ++dt)
      for (int j = 0; j < 4; ++j) {
        int row = b * 2048 + wrow + rt * 16 + lq * 4 + j;
        int col = h * 64 + dt * 16 + l15;
        float v = o[rt][dt][j] / lrun[rt][j];
        O[(size_t)row * 512 + col] = f2bf(v);
      }
}

extern "C" void kernel_launch(void* const* d_in, const int* in_sizes, int n_in,
                              void* d_out, int out_size, void* d_ws, size_t ws_size,
                              hipStream_t stream) {
  const float* x       = (const float*)d_in[0];
  const float* context = (const float*)d_in[1];
  const int*   mask    = (const int*)d_in[2];
  const float* Wq      = (const float*)d_in[3];
  const float* Wkv     = (const float*)d_in[4];
  const float* Wo      = (const float*)d_in[5];
  const float* bo      = (const float*)d_in[6];
  float* out = (float*)d_out;

  char* ws = (char*)d_ws;
  unsigned short* Wq_t  = (unsigned short*)(ws + 0);         //  512x512  bf16
  unsigned short* Wkv_t = (unsigned short*)(ws + 524288);    // 1024x512  bf16
  unsigned short* Wo_t  = (unsigned short*)(ws + 1572864);   //  512x512  bf16
  unsigned short* qb    = (unsigned short*)(ws + 2097152);   // 8192x512  bf16
  unsigned short* kb    = (unsigned short*)(ws + 10485760);  // 8192x512  bf16
  unsigned short* vtb   = (unsigned short*)(ws + 18874368);  // (b,h,d)x2048 bf16
  unsigned short* ab    = (unsigned short*)(ws + 27262976);  // 8192x512  bf16
  // total ws use: 35,651,584 bytes

  tcast_kernel<<<dim3(8, 8), 256, 0, stream>>>(Wq, Wq_t, 512, 512);
  tcast_kernel<<<dim3(16, 8), 256, 0, stream>>>(Wkv, Wkv_t, 512, 1024);
  tcast_kernel<<<dim3(8, 8), 256, 0, stream>>>(Wo, Wo_t, 512, 512);
  gemm_kernel<0, true><<<dim3(4, 64), 256, 0, stream>>>(x, Wq_t, qb, nullptr, nullptr, 8192, 512, 512);
  gemm_kernel<1, true><<<dim3(8, 64), 256, 0, stream>>>(context, Wkv_t, kb, vtb, nullptr, 8192, 1024, 512);
  attn_kernel<<<dim3(32, 16), 256, 0, stream>>>(qb, kb, vtb, mask, ab, 0.125f);
  gemm_kernel<2, false><<<dim3(4, 64), 256, 0, stream>>>(ab, Wo_t, out, nullptr, bo, 8192, 512, 512);
}